// Round 1
// baseline (1236.082 us; speedup 1.0000x reference)
//
#include <hip/hip_runtime.h>
#include <stdint.h>

#define H 128
#define TM 16

typedef __attribute__((ext_vector_type(8))) short short8;
typedef __attribute__((ext_vector_type(4))) float f32x4;

__device__ __forceinline__ unsigned short f2bf(float f) {
    union { float f; unsigned u; } v; v.f = f;
    unsigned u = v.u;
    u += 0x7fffu + ((u >> 16) & 1u);   // round-to-nearest-even
    return (unsigned short)(u >> 16);
}

__device__ __forceinline__ short8 cvt8(f32x4 a, f32x4 b) {
    short8 r;
    r[0] = (short)f2bf(a.x); r[1] = (short)f2bf(a.y);
    r[2] = (short)f2bf(a.z); r[3] = (short)f2bf(a.w);
    r[4] = (short)f2bf(b.x); r[5] = (short)f2bf(b.y);
    r[6] = (short)f2bf(b.z); r[7] = (short)f2bf(b.w);
    return r;
}

// ---------------------------------------------------------------------------
// Phase 1: agg[dst] += x[src] + emb[type].  32 lanes per edge, float4/lane.
// ---------------------------------------------------------------------------
__global__ __launch_bounds__(256) void scatter_kernel(
    const float* __restrict__ x, const int* __restrict__ ei,
    const int* __restrict__ et, const float* __restrict__ emb,
    float* __restrict__ agg, int E)
{
    int g = blockIdx.x * 256 + threadIdx.x;
    int e = g >> 5;
    int l = g & 31;
    if (e >= E) return;
    int src = ei[e];
    int dst = ei[E + e];
    int t   = et[e];
    f32x4 xv = *(const f32x4*)(x   + (size_t)src * H + l * 4);
    f32x4 ev = *(const f32x4*)(emb + (size_t)t   * H + l * 4);
    float* b = agg + (size_t)dst * H + l * 4;
    atomicAdd(b + 0, xv.x + ev.x);
    atomicAdd(b + 1, xv.y + ev.y);
    atomicAdd(b + 2, xv.z + ev.z);
    atomicAdd(b + 3, xv.w + ev.w);
}

// ---------------------------------------------------------------------------
// Phase 2: out = LN(relu([x|agg] @ [Wself^T;Wmsg^T] + bself + bmsg))
// One GEMM, K=256, bf16 MFMA 16x16x32. Weights live in registers per wave.
// Block = 256 threads = 4 waves; each wave owns 2 strips of 16 features.
// agg is read from d_out and the final result overwrites the same rows.
// ---------------------------------------------------------------------------
__global__ __launch_bounds__(256) void gemm_ln_kernel(
    const float* __restrict__ x, const float* __restrict__ Wself,
    const float* __restrict__ bself, const float* __restrict__ Wmsg,
    const float* __restrict__ bmsg, const float* __restrict__ gamma,
    const float* __restrict__ beta, float* __restrict__ agg_out,
    int nTiles)
{
    __shared__ __align__(16) short a_stage[TM * 264];  // 16 x (256+8 pad) bf16
    __shared__ __align__(16) float o_stage[TM * 132];  // 16 x (128+4 pad) f32

    const int tid  = threadIdx.x;
    const int wave = tid >> 6;
    const int lane = tid & 63;
    const int col  = lane & 15;
    const int quad = lane >> 4;

    // ---- B fragments (weights, bf16) into registers; once per block ----
    short8 bfrag[2][8];
    float bias[2];
#pragma unroll
    for (int s = 0; s < 2; ++s) {
        const int h = (wave * 2 + s) * 16 + col;
        bias[s] = bself[h] + bmsg[h];
#pragma unroll
        for (int kst = 0; kst < 8; ++kst) {
            const float* W = (kst < 4) ? Wself : Wmsg;
            const int k0 = (kst & 3) * 32 + quad * 8;
            const float* p = W + (size_t)h * H + k0;
            f32x4 w0 = *(const f32x4*)(p);
            f32x4 w1 = *(const f32x4*)(p + 4);
            bfrag[s][kst] = cvt8(w0, w1);
        }
    }

    // LN lane assignment: thread covers node (tid>>4), features f0..f0+7
    const int lnode = tid >> 4;
    const int f0 = (tid & 15) * 8;
    f32x4 g0  = *(const f32x4*)(gamma + f0);
    f32x4 g1  = *(const f32x4*)(gamma + f0 + 4);
    f32x4 be0 = *(const f32x4*)(beta + f0);
    f32x4 be1 = *(const f32x4*)(beta + f0 + 4);

    for (int tile = blockIdx.x; tile < nTiles; tile += gridDim.x) {
        const size_t rowBase = (size_t)tile * TM;

        // ---- stage A = [x | agg] rows as bf16 into LDS ----
        {
            const int node = tid >> 4;
            const int seg  = tid & 15;
            const int k0   = seg * 16;
            const float* src = (seg < 8)
                ? (x       + (rowBase + node) * H + k0)
                : (agg_out + (rowBase + node) * H + (k0 - 128));
            f32x4 v0 = ((const f32x4*)src)[0];
            f32x4 v1 = ((const f32x4*)src)[1];
            f32x4 v2 = ((const f32x4*)src)[2];
            f32x4 v3 = ((const f32x4*)src)[3];
            *(short8*)(&a_stage[node * 264 + k0])     = cvt8(v0, v1);
            *(short8*)(&a_stage[node * 264 + k0 + 8]) = cvt8(v2, v3);
        }
        __syncthreads();

        // ---- A fragments + MFMA over K=256 ----
        short8 afr[8];
#pragma unroll
        for (int kst = 0; kst < 8; ++kst)
            afr[kst] = *(const short8*)(&a_stage[col * 264 + kst * 32 + quad * 8]);

        f32x4 acc0 = {0.f, 0.f, 0.f, 0.f};
        f32x4 acc1 = {0.f, 0.f, 0.f, 0.f};
#pragma unroll
        for (int kst = 0; kst < 8; ++kst) {
            acc0 = __builtin_amdgcn_mfma_f32_16x16x32_bf16(afr[kst], bfrag[0][kst], acc0, 0, 0, 0);
            acc1 = __builtin_amdgcn_mfma_f32_16x16x32_bf16(afr[kst], bfrag[1][kst], acc1, 0, 0, 0);
        }

        // ---- bias + relu -> o_stage ----
#pragma unroll
        for (int s = 0; s < 2; ++s) {
            const int h = (wave * 2 + s) * 16 + col;
            f32x4 a = s ? acc1 : acc0;
#pragma unroll
            for (int r = 0; r < 4; ++r) {
                const int m = quad * 4 + r;
                float v = a[r] + bias[s];
                o_stage[m * 132 + h] = v > 0.f ? v : 0.f;
            }
        }
        __syncthreads();

        // ---- LayerNorm per node (16 lanes per node, 8 feats/lane) ----
        float v[8];
        float s1 = 0.f, s2 = 0.f;
#pragma unroll
        for (int j = 0; j < 8; ++j) {
            v[j] = o_stage[lnode * 132 + f0 + j];
            s1 += v[j];
            s2 += v[j] * v[j];
        }
#pragma unroll
        for (int m = 1; m < 16; m <<= 1) {
            s1 += __shfl_xor(s1, m, 64);
            s2 += __shfl_xor(s2, m, 64);
        }
        const float mu = s1 * (1.f / 128.f);
        const float var = s2 * (1.f / 128.f) - mu * mu;
        const float rstd = rsqrtf(var + 1e-5f);

        f32x4 o0, o1;
        o0.x = (v[0] - mu) * rstd * g0.x + be0.x;
        o0.y = (v[1] - mu) * rstd * g0.y + be0.y;
        o0.z = (v[2] - mu) * rstd * g0.z + be0.z;
        o0.w = (v[3] - mu) * rstd * g0.w + be0.w;
        o1.x = (v[4] - mu) * rstd * g1.x + be1.x;
        o1.y = (v[5] - mu) * rstd * g1.y + be1.y;
        o1.z = (v[6] - mu) * rstd * g1.z + be1.z;
        o1.w = (v[7] - mu) * rstd * g1.w + be1.w;

        float* dst = agg_out + (rowBase + lnode) * H + f0;
        *(f32x4*)(dst)     = o0;
        *(f32x4*)(dst + 4) = o1;
        // no trailing barrier needed: next iter's first __syncthreads()
        // separates these o_stage reads from the next epilogue writes.
    }
}

extern "C" void kernel_launch(void* const* d_in, const int* in_sizes, int n_in,
                              void* d_out, int out_size, void* d_ws, size_t ws_size,
                              hipStream_t stream) {
    const float* x     = (const float*)d_in[0];
    const int*   ei    = (const int*)d_in[1];
    const int*   et    = (const int*)d_in[2];
    const float* emb   = (const float*)d_in[3];
    const float* Wself = (const float*)d_in[4];
    const float* bself = (const float*)d_in[5];
    const float* Wmsg  = (const float*)d_in[6];
    const float* bmsg  = (const float*)d_in[7];
    const float* gamma = (const float*)d_in[8];
    const float* beta  = (const float*)d_in[9];
    float* out = (float*)d_out;

    const int E = in_sizes[2];
    const int N = in_sizes[0] / H;

    // d_out doubles as the aggregation buffer; zero it first.
    hipMemsetAsync(out, 0, (size_t)N * H * sizeof(float), stream);

    const long long sthreads = (long long)E * 32;
    scatter_kernel<<<(int)((sthreads + 255) / 256), 256, 0, stream>>>(
        x, ei, et, emb, out, E);

    const int nTiles = N / TM;   // N = 200000 -> 12500, exact
    int grid = 2500;
    if (grid > nTiles) grid = nTiles;
    gemm_ln_kernel<<<grid, 256, 0, stream>>>(
        x, Wself, bself, Wmsg, bmsg, gamma, beta, out, nTiles);
}

// Round 2
// 384.962 us; speedup vs baseline: 3.2109x; 3.2109x over previous
//
#include <hip/hip_runtime.h>
#include <stdint.h>

#define H 128
#define TM 16
#define MAXDEG 24
#define OVF_CAP 8192

typedef __attribute__((ext_vector_type(8))) short short8;
typedef __attribute__((ext_vector_type(4))) float f32x4;

__device__ __forceinline__ unsigned short f2bf(float f) {
    union { float f; unsigned u; } v; v.f = f;
    unsigned u = v.u;
    u += 0x7fffu + ((u >> 16) & 1u);   // round-to-nearest-even
    return (unsigned short)(u >> 16);
}

__device__ __forceinline__ short8 cvt8(f32x4 a, f32x4 b) {
    short8 r;
    r[0] = (short)f2bf(a.x); r[1] = (short)f2bf(a.y);
    r[2] = (short)f2bf(a.z); r[3] = (short)f2bf(a.w);
    r[4] = (short)f2bf(b.x); r[5] = (short)f2bf(b.y);
    r[6] = (short)f2bf(b.z); r[7] = (short)f2bf(b.w);
    return r;
}

// ---------------------------------------------------------------------------
// CSR-lite build: one thread per edge. Slot via int atomicAdd on cnt[dst];
// packed entry = src | (type << 18). Overflow (deg > MAXDEG) -> side list.
// ---------------------------------------------------------------------------
__global__ __launch_bounds__(256) void build_kernel(
    const int* __restrict__ ei, const int* __restrict__ et,
    int* __restrict__ cnt, int* __restrict__ ovf_cnt, int* __restrict__ ovf,
    int* __restrict__ bucket, int E)
{
    int e = blockIdx.x * 256 + threadIdx.x;
    if (e >= E) return;
    int src = ei[e];
    int dst = ei[E + e];
    int t   = et[e];
    int packed = src | (t << 18);
    int pos = atomicAdd(&cnt[dst], 1);
    if (pos < MAXDEG) {
        bucket[(size_t)dst * MAXDEG + pos] = packed;
    } else {
        int o = atomicAdd(ovf_cnt, 1);
        if (o < OVF_CAP) { ovf[2 * o] = dst; ovf[2 * o + 1] = packed; }
    }
}

// ---------------------------------------------------------------------------
// Aggregate: 32 lanes per node, f32x4 per lane. Each agg row written ONCE
// (zeros for isolated nodes) -> no memset of d_out needed.
// ---------------------------------------------------------------------------
__global__ __launch_bounds__(256) void aggregate_kernel(
    const float* __restrict__ x, const float* __restrict__ emb,
    const int* __restrict__ cnt, const int* __restrict__ bucket,
    float* __restrict__ agg, int N)
{
    int g = blockIdx.x * 256 + threadIdx.x;
    int node = g >> 5;
    int l = g & 31;
    if (node >= N) return;
    int c = cnt[node];
    if (c > MAXDEG) c = MAXDEG;
    f32x4 acc = {0.f, 0.f, 0.f, 0.f};
    const int* b = bucket + (size_t)node * MAXDEG;
    for (int i = 0; i < c; ++i) {
        int p = b[i];
        int src = p & 0x3FFFF;
        int t = p >> 18;
        f32x4 xv = *(const f32x4*)(x   + (size_t)src * H + l * 4);
        f32x4 ev = *(const f32x4*)(emb + (size_t)t   * H + l * 4);
        acc.x += xv.x + ev.x; acc.y += xv.y + ev.y;
        acc.z += xv.z + ev.z; acc.w += xv.w + ev.w;
    }
    *(f32x4*)(agg + (size_t)node * H + l * 4) = acc;
}

// Drain overflow entries (normally zero) with atomics.
__global__ __launch_bounds__(256) void drain_kernel(
    const float* __restrict__ x, const float* __restrict__ emb,
    const int* __restrict__ ovf_cnt, const int* __restrict__ ovf,
    float* __restrict__ agg)
{
    int g = blockIdx.x * 256 + threadIdx.x;
    int i = g >> 5;
    int l = g & 31;
    int n = *ovf_cnt;
    if (n > OVF_CAP) n = OVF_CAP;
    if (i >= n) return;
    int dst = ovf[2 * i];
    int p   = ovf[2 * i + 1];
    int src = p & 0x3FFFF;
    int t = p >> 18;
    f32x4 xv = *(const f32x4*)(x   + (size_t)src * H + l * 4);
    f32x4 ev = *(const f32x4*)(emb + (size_t)t   * H + l * 4);
    float* d = agg + (size_t)dst * H + l * 4;
    atomicAdd(d + 0, xv.x + ev.x);
    atomicAdd(d + 1, xv.y + ev.y);
    atomicAdd(d + 2, xv.z + ev.z);
    atomicAdd(d + 3, xv.w + ev.w);
}

// ---------------------------------------------------------------------------
// Fallback scatter (atomics) if ws is too small / N too big for packing.
// ---------------------------------------------------------------------------
__global__ __launch_bounds__(256) void scatter_kernel(
    const float* __restrict__ x, const int* __restrict__ ei,
    const int* __restrict__ et, const float* __restrict__ emb,
    float* __restrict__ agg, int E)
{
    int g = blockIdx.x * 256 + threadIdx.x;
    int e = g >> 5;
    int l = g & 31;
    if (e >= E) return;
    int src = ei[e];
    int dst = ei[E + e];
    int t   = et[e];
    f32x4 xv = *(const f32x4*)(x   + (size_t)src * H + l * 4);
    f32x4 ev = *(const f32x4*)(emb + (size_t)t   * H + l * 4);
    float* b = agg + (size_t)dst * H + l * 4;
    atomicAdd(b + 0, xv.x + ev.x);
    atomicAdd(b + 1, xv.y + ev.y);
    atomicAdd(b + 2, xv.z + ev.z);
    atomicAdd(b + 3, xv.w + ev.w);
}

// ---------------------------------------------------------------------------
// out = LN(relu([x|agg] @ [Wself^T;Wmsg^T] + bself + bmsg))
// One GEMM, K=256, bf16 MFMA 16x16x32. Weights in registers per wave.
// agg is read from d_out; result overwrites the same rows (barrier-safe).
// ---------------------------------------------------------------------------
__global__ __launch_bounds__(256) void gemm_ln_kernel(
    const float* __restrict__ x, const float* __restrict__ Wself,
    const float* __restrict__ bself, const float* __restrict__ Wmsg,
    const float* __restrict__ bmsg, const float* __restrict__ gamma,
    const float* __restrict__ beta, float* __restrict__ agg_out,
    int nTiles)
{
    __shared__ __align__(16) short a_stage[TM * 264];  // 16 x (256+8 pad) bf16
    __shared__ __align__(16) float o_stage[TM * 132];  // 16 x (128+4 pad) f32

    const int tid  = threadIdx.x;
    const int wave = tid >> 6;
    const int lane = tid & 63;
    const int col  = lane & 15;
    const int quad = lane >> 4;

    // ---- B fragments (weights, bf16) into registers; once per block ----
    short8 bfrag[2][8];
    float bias[2];
#pragma unroll
    for (int s = 0; s < 2; ++s) {
        const int h = (wave * 2 + s) * 16 + col;
        bias[s] = bself[h] + bmsg[h];
#pragma unroll
        for (int kst = 0; kst < 8; ++kst) {
            const float* W = (kst < 4) ? Wself : Wmsg;
            const int k0 = (kst & 3) * 32 + quad * 8;
            const float* p = W + (size_t)h * H + k0;
            f32x4 w0 = *(const f32x4*)(p);
            f32x4 w1 = *(const f32x4*)(p + 4);
            bfrag[s][kst] = cvt8(w0, w1);
        }
    }

    const int lnode = tid >> 4;
    const int f0 = (tid & 15) * 8;
    f32x4 g0  = *(const f32x4*)(gamma + f0);
    f32x4 g1  = *(const f32x4*)(gamma + f0 + 4);
    f32x4 be0 = *(const f32x4*)(beta + f0);
    f32x4 be1 = *(const f32x4*)(beta + f0 + 4);

    for (int tile = blockIdx.x; tile < nTiles; tile += gridDim.x) {
        const size_t rowBase = (size_t)tile * TM;

        // ---- stage A = [x | agg] rows as bf16 into LDS ----
        {
            const int node = tid >> 4;
            const int seg  = tid & 15;
            const int k0   = seg * 16;
            const float* src = (seg < 8)
                ? (x       + (rowBase + node) * H + k0)
                : (agg_out + (rowBase + node) * H + (k0 - 128));
            f32x4 v0 = ((const f32x4*)src)[0];
            f32x4 v1 = ((const f32x4*)src)[1];
            f32x4 v2 = ((const f32x4*)src)[2];
            f32x4 v3 = ((const f32x4*)src)[3];
            *(short8*)(&a_stage[node * 264 + k0])     = cvt8(v0, v1);
            *(short8*)(&a_stage[node * 264 + k0 + 8]) = cvt8(v2, v3);
        }
        __syncthreads();

        short8 afr[8];
#pragma unroll
        for (int kst = 0; kst < 8; ++kst)
            afr[kst] = *(const short8*)(&a_stage[col * 264 + kst * 32 + quad * 8]);

        f32x4 acc0 = {0.f, 0.f, 0.f, 0.f};
        f32x4 acc1 = {0.f, 0.f, 0.f, 0.f};
#pragma unroll
        for (int kst = 0; kst < 8; ++kst) {
            acc0 = __builtin_amdgcn_mfma_f32_16x16x32_bf16(afr[kst], bfrag[0][kst], acc0, 0, 0, 0);
            acc1 = __builtin_amdgcn_mfma_f32_16x16x32_bf16(afr[kst], bfrag[1][kst], acc1, 0, 0, 0);
        }

#pragma unroll
        for (int s = 0; s < 2; ++s) {
            const int h = (wave * 2 + s) * 16 + col;
            f32x4 a = s ? acc1 : acc0;
#pragma unroll
            for (int r = 0; r < 4; ++r) {
                const int m = quad * 4 + r;
                float v = a[r] + bias[s];
                o_stage[m * 132 + h] = v > 0.f ? v : 0.f;
            }
        }
        __syncthreads();

        float v[8];
        float s1 = 0.f, s2 = 0.f;
#pragma unroll
        for (int j = 0; j < 8; ++j) {
            v[j] = o_stage[lnode * 132 + f0 + j];
            s1 += v[j];
            s2 += v[j] * v[j];
        }
#pragma unroll
        for (int m = 1; m < 16; m <<= 1) {
            s1 += __shfl_xor(s1, m, 64);
            s2 += __shfl_xor(s2, m, 64);
        }
        const float mu = s1 * (1.f / 128.f);
        const float var = s2 * (1.f / 128.f) - mu * mu;
        const float rstd = rsqrtf(var + 1e-5f);

        f32x4 o0, o1;
        o0.x = (v[0] - mu) * rstd * g0.x + be0.x;
        o0.y = (v[1] - mu) * rstd * g0.y + be0.y;
        o0.z = (v[2] - mu) * rstd * g0.z + be0.z;
        o0.w = (v[3] - mu) * rstd * g0.w + be0.w;
        o1.x = (v[4] - mu) * rstd * g1.x + be1.x;
        o1.y = (v[5] - mu) * rstd * g1.y + be1.y;
        o1.z = (v[6] - mu) * rstd * g1.z + be1.z;
        o1.w = (v[7] - mu) * rstd * g1.w + be1.w;

        float* dst = agg_out + (rowBase + lnode) * H + f0;
        *(f32x4*)(dst)     = o0;
        *(f32x4*)(dst + 4) = o1;
    }
}

extern "C" void kernel_launch(void* const* d_in, const int* in_sizes, int n_in,
                              void* d_out, int out_size, void* d_ws, size_t ws_size,
                              hipStream_t stream) {
    const float* x     = (const float*)d_in[0];
    const int*   ei    = (const int*)d_in[1];
    const int*   et    = (const int*)d_in[2];
    const float* emb   = (const float*)d_in[3];
    const float* Wself = (const float*)d_in[4];
    const float* bself = (const float*)d_in[5];
    const float* Wmsg  = (const float*)d_in[6];
    const float* bmsg  = (const float*)d_in[7];
    const float* gamma = (const float*)d_in[8];
    const float* beta  = (const float*)d_in[9];
    float* out = (float*)d_out;

    const int E = in_sizes[2];
    const int N = in_sizes[0] / H;

    // ws layout: [cnt: N ints][ovf_cnt: 1][ovf: 2*OVF_CAP][bucket: N*MAXDEG]
    const size_t need = ((size_t)N * (1 + MAXDEG) + 1 + 2 * OVF_CAP) * sizeof(int);
    const bool use_csr = (ws_size >= need) && (N <= (1 << 18));

    if (use_csr) {
        int* cnt     = (int*)d_ws;
        int* ovf_cnt = cnt + N;
        int* ovf     = cnt + N + 1;
        int* bucket  = ovf + 2 * OVF_CAP;

        hipMemsetAsync(cnt, 0, (size_t)(N + 1) * sizeof(int), stream);
        build_kernel<<<(E + 255) / 256, 256, 0, stream>>>(
            ei, et, cnt, ovf_cnt, ovf, bucket, E);
        aggregate_kernel<<<(N * 32 + 255) / 256, 256, 0, stream>>>(
            x, emb, cnt, bucket, out, N);
        drain_kernel<<<(OVF_CAP * 32) / 256, 256, 0, stream>>>(
            x, emb, ovf_cnt, ovf, out);
    } else {
        hipMemsetAsync(out, 0, (size_t)N * H * sizeof(float), stream);
        const long long sthreads = (long long)E * 32;
        scatter_kernel<<<(int)((sthreads + 255) / 256), 256, 0, stream>>>(
            x, ei, et, emb, out, E);
    }

    const int nTiles = N / TM;
    int grid = 2500;
    if (grid > nTiles) grid = nTiles;
    gemm_ln_kernel<<<grid, 256, 0, stream>>>(
        x, Wself, bself, Wmsg, bmsg, gamma, beta, out, nTiles);
}

// Round 3
// 339.615 us; speedup vs baseline: 3.6397x; 1.1335x over previous
//
#include <hip/hip_runtime.h>
#include <stdint.h>

#define H 128
#define TM 16
#define MAXDEG 24
#define OVF_CAP 4096

typedef __attribute__((ext_vector_type(8))) short short8;
typedef __attribute__((ext_vector_type(4))) float f32x4;
typedef __attribute__((ext_vector_type(4))) int i32x4;

__device__ __forceinline__ unsigned short f2bf(float f) {
    union { float f; unsigned u; } v; v.f = f;
    unsigned u = v.u;
    u += 0x7fffu + ((u >> 16) & 1u);   // round-to-nearest-even
    return (unsigned short)(u >> 16);
}

__device__ __forceinline__ float bf2f(unsigned short u) {
    union { unsigned u; float f; } v; v.u = ((unsigned)u) << 16; return v.f;
}

__device__ __forceinline__ short8 cvt8(f32x4 a, f32x4 b) {
    short8 r;
    r[0] = (short)f2bf(a.x); r[1] = (short)f2bf(a.y);
    r[2] = (short)f2bf(a.z); r[3] = (short)f2bf(a.w);
    r[4] = (short)f2bf(b.x); r[5] = (short)f2bf(b.y);
    r[6] = (short)f2bf(b.z); r[7] = (short)f2bf(b.w);
    return r;
}

// ---------------------------------------------------------------------------
// fp32 -> bf16 for x (N*H) and emb (16*H), packed 8 elements/thread.
// ---------------------------------------------------------------------------
__global__ __launch_bounds__(256) void convert_kernel(
    const float* __restrict__ x, const float* __restrict__ emb,
    unsigned short* __restrict__ xb, unsigned short* __restrict__ embb,
    int total8x, int total8e)
{
    int i = blockIdx.x * 256 + threadIdx.x;
    if (i < total8x) {
        f32x4 a = ((const f32x4*)x)[2 * i];
        f32x4 b = ((const f32x4*)x)[2 * i + 1];
        ((short8*)xb)[i] = cvt8(a, b);
    } else if (i < total8x + total8e) {
        int j = i - total8x;
        f32x4 a = ((const f32x4*)emb)[2 * j];
        f32x4 b = ((const f32x4*)emb)[2 * j + 1];
        ((short8*)embb)[j] = cvt8(a, b);
    }
}

// ---------------------------------------------------------------------------
// CSR-lite build: one thread per edge; packed entry = src | (type << 18).
// ---------------------------------------------------------------------------
__global__ __launch_bounds__(256) void build_kernel(
    const int* __restrict__ ei, const int* __restrict__ et,
    int* __restrict__ cnt, int* __restrict__ ovf_cnt, int* __restrict__ ovf,
    int* __restrict__ bucket, int E)
{
    int e = blockIdx.x * 256 + threadIdx.x;
    if (e >= E) return;
    int src = ei[e];
    int dst = ei[E + e];
    int t   = et[e];
    int packed = src | (t << 18);
    int pos = atomicAdd(&cnt[dst], 1);
    if (pos < MAXDEG) {
        bucket[(size_t)dst * MAXDEG + pos] = packed;
    } else {
        int o = atomicAdd(ovf_cnt, 1);
        if (o < OVF_CAP) { ovf[2 * o] = dst; ovf[2 * o + 1] = packed; }
    }
}

// ---------------------------------------------------------------------------
// Aggregate (bf16): 16 lanes/node, short8 per lane per row; edges in chunks
// of 4 -> 4 concurrent gathers per lane; fp32 accumulate; bf16 write-once.
// ---------------------------------------------------------------------------
__device__ __forceinline__ void accum_edge(float* acc, short8 xv, short8 ev) {
#pragma unroll
    for (int j = 0; j < 8; ++j)
        acc[j] += bf2f((unsigned short)xv[j]) + bf2f((unsigned short)ev[j]);
}

__global__ __launch_bounds__(256) void aggregate_bf16_kernel(
    const unsigned short* __restrict__ xb, const unsigned short* __restrict__ embb,
    const int* __restrict__ cnt, const int* __restrict__ bucket,
    unsigned short* __restrict__ aggb, int N)
{
    int g = blockIdx.x * 256 + threadIdx.x;
    int node = g >> 4;
    int l = g & 15;
    if (node >= N) return;
    int c = cnt[node];
    if (c > MAXDEG) c = MAXDEG;

    float acc[8] = {0.f, 0.f, 0.f, 0.f, 0.f, 0.f, 0.f, 0.f};
    const int* b = bucket + (size_t)node * MAXDEG;

    for (int i0 = 0; i0 < c; i0 += 4) {
        i32x4 p = *(const i32x4*)(b + i0);
        int rem = c - i0;
        bool g1 = rem > 1, g2 = rem > 2, g3 = rem > 3;
        short8 xv0, xv1, xv2, xv3;
        short8 ev0, ev1, ev2, ev3;
        {
            int s = p.x & 0x3FFFF, t = p.x >> 18;
            xv0 = *(const short8*)(xb + (size_t)s * H + l * 8);
            ev0 = *(const short8*)(embb + t * H + l * 8);
        }
        if (g1) {
            int s = p.y & 0x3FFFF, t = p.y >> 18;
            xv1 = *(const short8*)(xb + (size_t)s * H + l * 8);
            ev1 = *(const short8*)(embb + t * H + l * 8);
        }
        if (g2) {
            int s = p.z & 0x3FFFF, t = p.z >> 18;
            xv2 = *(const short8*)(xb + (size_t)s * H + l * 8);
            ev2 = *(const short8*)(embb + t * H + l * 8);
        }
        if (g3) {
            int s = p.w & 0x3FFFF, t = p.w >> 18;
            xv3 = *(const short8*)(xb + (size_t)s * H + l * 8);
            ev3 = *(const short8*)(embb + t * H + l * 8);
        }
        accum_edge(acc, xv0, ev0);
        if (g1) accum_edge(acc, xv1, ev1);
        if (g2) accum_edge(acc, xv2, ev2);
        if (g3) accum_edge(acc, xv3, ev3);
    }

    short8 r;
#pragma unroll
    for (int j = 0; j < 8; ++j) r[j] = (short)f2bf(acc[j]);
    *(short8*)(aggb + (size_t)node * H + l * 8) = r;
}

// Serial overflow drain (normally n==0). One block, 128 threads = features.
__global__ __launch_bounds__(128) void drain_bf16_kernel(
    const unsigned short* __restrict__ xb, const float* __restrict__ emb,
    const int* __restrict__ ovf_cnt, const int* __restrict__ ovf,
    unsigned short* __restrict__ aggb)
{
    int j = threadIdx.x;
    int n = *ovf_cnt;
    if (n > OVF_CAP) n = OVF_CAP;
    for (int i = 0; i < n; ++i) {
        int dst = ovf[2 * i];
        int p   = ovf[2 * i + 1];
        int src = p & 0x3FFFF;
        int t = p >> 18;
        float v = bf2f(aggb[(size_t)dst * H + j]) + bf2f(xb[(size_t)src * H + j])
                + emb[t * H + j];
        aggb[(size_t)dst * H + j] = f2bf(v);
    }
}

// ---------------------------------------------------------------------------
// Tier-B fallback kernels (R2 path, fp32 agg in d_out)
// ---------------------------------------------------------------------------
__global__ __launch_bounds__(256) void aggregate_f32_kernel(
    const float* __restrict__ x, const float* __restrict__ emb,
    const int* __restrict__ cnt, const int* __restrict__ bucket,
    float* __restrict__ agg, int N)
{
    int g = blockIdx.x * 256 + threadIdx.x;
    int node = g >> 5;
    int l = g & 31;
    if (node >= N) return;
    int c = cnt[node];
    if (c > MAXDEG) c = MAXDEG;
    f32x4 acc = {0.f, 0.f, 0.f, 0.f};
    const int* b = bucket + (size_t)node * MAXDEG;
    for (int i = 0; i < c; ++i) {
        int p = b[i];
        int src = p & 0x3FFFF;
        int t = p >> 18;
        f32x4 xv = *(const f32x4*)(x   + (size_t)src * H + l * 4);
        f32x4 ev = *(const f32x4*)(emb + (size_t)t   * H + l * 4);
        acc.x += xv.x + ev.x; acc.y += xv.y + ev.y;
        acc.z += xv.z + ev.z; acc.w += xv.w + ev.w;
    }
    *(f32x4*)(agg + (size_t)node * H + l * 4) = acc;
}

__global__ __launch_bounds__(256) void drain_f32_kernel(
    const float* __restrict__ x, const float* __restrict__ emb,
    const int* __restrict__ ovf_cnt, const int* __restrict__ ovf,
    float* __restrict__ agg)
{
    int g = blockIdx.x * 256 + threadIdx.x;
    int i = g >> 5;
    int l = g & 31;
    int n = *ovf_cnt;
    if (n > OVF_CAP) n = OVF_CAP;
    if (i >= n) return;
    int dst = ovf[2 * i];
    int p   = ovf[2 * i + 1];
    int src = p & 0x3FFFF;
    int t = p >> 18;
    f32x4 xv = *(const f32x4*)(x   + (size_t)src * H + l * 4);
    f32x4 ev = *(const f32x4*)(emb + (size_t)t   * H + l * 4);
    float* d = agg + (size_t)dst * H + l * 4;
    atomicAdd(d + 0, xv.x + ev.x);
    atomicAdd(d + 1, xv.y + ev.y);
    atomicAdd(d + 2, xv.z + ev.z);
    atomicAdd(d + 3, xv.w + ev.w);
}

// Tier-C fallback: plain atomic scatter.
__global__ __launch_bounds__(256) void scatter_kernel(
    const float* __restrict__ x, const int* __restrict__ ei,
    const int* __restrict__ et, const float* __restrict__ emb,
    float* __restrict__ agg, int E)
{
    int g = blockIdx.x * 256 + threadIdx.x;
    int e = g >> 5;
    int l = g & 31;
    if (e >= E) return;
    int src = ei[e];
    int dst = ei[E + e];
    int t   = et[e];
    f32x4 xv = *(const f32x4*)(x   + (size_t)src * H + l * 4);
    f32x4 ev = *(const f32x4*)(emb + (size_t)t   * H + l * 4);
    float* b = agg + (size_t)dst * H + l * 4;
    atomicAdd(b + 0, xv.x + ev.x);
    atomicAdd(b + 1, xv.y + ev.y);
    atomicAdd(b + 2, xv.z + ev.z);
    atomicAdd(b + 3, xv.w + ev.w);
}

// ---------------------------------------------------------------------------
// out = LN(relu([x|agg] @ [Wself^T;Wmsg^T] + bself + bmsg))
// K=256 bf16 MFMA 16x16x32; weights in registers per wave.
// BF16IN: x/agg staged from bf16 ws buffers. Else: fp32 x + agg in `out`
// (rows overwritten after barrier; block-local, safe).
// ---------------------------------------------------------------------------
template<bool BF16IN>
__global__ __launch_bounds__(256) void gemm_ln_kernel(
    const float* __restrict__ x, const unsigned short* __restrict__ xb,
    const unsigned short* __restrict__ aggb,
    const float* __restrict__ Wself, const float* __restrict__ bself,
    const float* __restrict__ Wmsg, const float* __restrict__ bmsg,
    const float* __restrict__ gamma, const float* __restrict__ beta,
    float* __restrict__ out, int nTiles)
{
    __shared__ __align__(16) short a_stage[TM * 264];  // 16 x (256+8 pad) bf16
    __shared__ __align__(16) float o_stage[TM * 132];  // 16 x (128+4 pad) f32

    const int tid  = threadIdx.x;
    const int wave = tid >> 6;
    const int lane = tid & 63;
    const int col  = lane & 15;
    const int quad = lane >> 4;

    short8 bfrag[2][8];
    float bias[2];
#pragma unroll
    for (int s = 0; s < 2; ++s) {
        const int h = (wave * 2 + s) * 16 + col;
        bias[s] = bself[h] + bmsg[h];
#pragma unroll
        for (int kst = 0; kst < 8; ++kst) {
            const float* W = (kst < 4) ? Wself : Wmsg;
            const int k0 = (kst & 3) * 32 + quad * 8;
            const float* p = W + (size_t)h * H + k0;
            f32x4 w0 = *(const f32x4*)(p);
            f32x4 w1 = *(const f32x4*)(p + 4);
            bfrag[s][kst] = cvt8(w0, w1);
        }
    }

    const int lnode = tid >> 4;
    const int f0 = (tid & 15) * 8;
    f32x4 g0  = *(const f32x4*)(gamma + f0);
    f32x4 g1  = *(const f32x4*)(gamma + f0 + 4);
    f32x4 be0 = *(const f32x4*)(beta + f0);
    f32x4 be1 = *(const f32x4*)(beta + f0 + 4);

    for (int tile = blockIdx.x; tile < nTiles; tile += gridDim.x) {
        const size_t rowBase = (size_t)tile * TM;

        {
            const int node = tid >> 4;
            const int seg  = tid & 15;
            if (BF16IN) {
                const size_t row = rowBase + node;
                const unsigned short* src = (seg < 8)
                    ? (xb   + row * H + seg * 16)
                    : (aggb + row * H + (seg - 8) * 16);
                short8 v0 = ((const short8*)src)[0];
                short8 v1 = ((const short8*)src)[1];
                *(short8*)(&a_stage[node * 264 + seg * 16])     = v0;
                *(short8*)(&a_stage[node * 264 + seg * 16 + 8]) = v1;
            } else {
                const int k0 = seg * 16;
                const float* src = (seg < 8)
                    ? (x   + (rowBase + node) * H + k0)
                    : (out + (rowBase + node) * H + (k0 - 128));
                f32x4 v0 = ((const f32x4*)src)[0];
                f32x4 v1 = ((const f32x4*)src)[1];
                f32x4 v2 = ((const f32x4*)src)[2];
                f32x4 v3 = ((const f32x4*)src)[3];
                *(short8*)(&a_stage[node * 264 + k0])     = cvt8(v0, v1);
                *(short8*)(&a_stage[node * 264 + k0 + 8]) = cvt8(v2, v3);
            }
        }
        __syncthreads();

        short8 afr[8];
#pragma unroll
        for (int kst = 0; kst < 8; ++kst)
            afr[kst] = *(const short8*)(&a_stage[col * 264 + kst * 32 + quad * 8]);

        f32x4 acc0 = {0.f, 0.f, 0.f, 0.f};
        f32x4 acc1 = {0.f, 0.f, 0.f, 0.f};
#pragma unroll
        for (int kst = 0; kst < 8; ++kst) {
            acc0 = __builtin_amdgcn_mfma_f32_16x16x32_bf16(afr[kst], bfrag[0][kst], acc0, 0, 0, 0);
            acc1 = __builtin_amdgcn_mfma_f32_16x16x32_bf16(afr[kst], bfrag[1][kst], acc1, 0, 0, 0);
        }

#pragma unroll
        for (int s = 0; s < 2; ++s) {
            const int h = (wave * 2 + s) * 16 + col;
            f32x4 a = s ? acc1 : acc0;
#pragma unroll
            for (int r = 0; r < 4; ++r) {
                const int m = quad * 4 + r;
                float v = a[r] + bias[s];
                o_stage[m * 132 + h] = v > 0.f ? v : 0.f;
            }
        }
        __syncthreads();

        float v[8];
        float s1 = 0.f, s2 = 0.f;
#pragma unroll
        for (int j = 0; j < 8; ++j) {
            v[j] = o_stage[lnode * 132 + f0 + j];
            s1 += v[j];
            s2 += v[j] * v[j];
        }
#pragma unroll
        for (int m = 1; m < 16; m <<= 1) {
            s1 += __shfl_xor(s1, m, 64);
            s2 += __shfl_xor(s2, m, 64);
        }
        const float mu = s1 * (1.f / 128.f);
        const float var = s2 * (1.f / 128.f) - mu * mu;
        const float rstd = rsqrtf(var + 1e-5f);

        f32x4 o0, o1;
        o0.x = (v[0] - mu) * rstd * g0.x + be0.x;
        o0.y = (v[1] - mu) * rstd * g0.y + be0.y;
        o0.z = (v[2] - mu) * rstd * g0.z + be0.z;
        o0.w = (v[3] - mu) * rstd * g0.w + be0.w;
        o1.x = (v[4] - mu) * rstd * g1.x + be1.x;
        o1.y = (v[5] - mu) * rstd * g1.y + be1.y;
        o1.z = (v[6] - mu) * rstd * g1.z + be1.z;
        o1.w = (v[7] - mu) * rstd * g1.w + be1.w;

        float* dst = out + (rowBase + lnode) * H + f0;
        *(f32x4*)(dst)     = o0;
        *(f32x4*)(dst + 4) = o1;
    }
}

extern "C" void kernel_launch(void* const* d_in, const int* in_sizes, int n_in,
                              void* d_out, int out_size, void* d_ws, size_t ws_size,
                              hipStream_t stream) {
    const float* x     = (const float*)d_in[0];
    const int*   ei    = (const int*)d_in[1];
    const int*   et    = (const int*)d_in[2];
    const float* emb   = (const float*)d_in[3];
    const float* Wself = (const float*)d_in[4];
    const float* bself = (const float*)d_in[5];
    const float* Wmsg  = (const float*)d_in[6];
    const float* bmsg  = (const float*)d_in[7];
    const float* gamma = (const float*)d_in[8];
    const float* beta  = (const float*)d_in[9];
    float* out = (float*)d_out;

    const int E = in_sizes[2];
    const int N = in_sizes[0] / H;
    const int nTiles = N / TM;
    int grid = 2500;
    if (grid > nTiles) grid = nTiles;

    auto rnd = [](size_t b) { return (b + 255) & ~(size_t)255; };
    const size_t sz_xb   = rnd((size_t)N * H * 2);
    const size_t sz_aggb = rnd((size_t)N * H * 2);
    const size_t sz_embb = rnd((size_t)16 * H * 2);
    const size_t sz_ints = rnd(((size_t)N + 1 + 2 * OVF_CAP) * 4);
    const size_t sz_bkt  = rnd((size_t)N * MAXDEG * 4);
    const size_t needA = sz_xb + sz_aggb + sz_embb + sz_ints + sz_bkt;
    const size_t needB = sz_ints + sz_bkt;
    const bool fits18 = (N <= (1 << 18));

    if (fits18 && ws_size >= needA) {
        // ---- Tier A: bf16 plane ----
        uint8_t* p = (uint8_t*)d_ws;
        unsigned short* xb   = (unsigned short*)p;           p += sz_xb;
        unsigned short* aggb = (unsigned short*)p;           p += sz_aggb;
        unsigned short* embb = (unsigned short*)p;           p += sz_embb;
        int* cnt     = (int*)p;                              p += sz_ints;
        int* ovf_cnt = cnt + N;
        int* ovf     = cnt + N + 1;
        int* bucket  = (int*)p;

        hipMemsetAsync(cnt, 0, (size_t)(N + 1) * sizeof(int), stream);
        const int t8x = N * H / 8, t8e = 16 * H / 8;
        convert_kernel<<<(t8x + t8e + 255) / 256, 256, 0, stream>>>(
            x, emb, xb, embb, t8x, t8e);
        build_kernel<<<(E + 255) / 256, 256, 0, stream>>>(
            ei, et, cnt, ovf_cnt, ovf, bucket, E);
        aggregate_bf16_kernel<<<(N * 16 + 255) / 256, 256, 0, stream>>>(
            xb, embb, cnt, bucket, aggb, N);
        drain_bf16_kernel<<<1, 128, 0, stream>>>(xb, emb, ovf_cnt, ovf, aggb);
        gemm_ln_kernel<true><<<grid, 256, 0, stream>>>(
            x, xb, aggb, Wself, bself, Wmsg, bmsg, gamma, beta, out, nTiles);
    } else if (fits18 && ws_size >= needB) {
        // ---- Tier B: fp32 agg in d_out (R2 path) ----
        uint8_t* p = (uint8_t*)d_ws;
        int* cnt     = (int*)p;                              p += sz_ints;
        int* ovf_cnt = cnt + N;
        int* ovf     = cnt + N + 1;
        int* bucket  = (int*)p;

        hipMemsetAsync(cnt, 0, (size_t)(N + 1) * sizeof(int), stream);
        build_kernel<<<(E + 255) / 256, 256, 0, stream>>>(
            ei, et, cnt, ovf_cnt, ovf, bucket, E);
        aggregate_f32_kernel<<<(N * 32 + 255) / 256, 256, 0, stream>>>(
            x, emb, cnt, bucket, out, N);
        drain_f32_kernel<<<(OVF_CAP * 32) / 256, 256, 0, stream>>>(
            x, emb, ovf_cnt, ovf, out);
        gemm_ln_kernel<false><<<grid, 256, 0, stream>>>(
            x, nullptr, nullptr, Wself, bself, Wmsg, bmsg, gamma, beta, out, nTiles);
    } else {
        // ---- Tier C: atomic scatter ----
        hipMemsetAsync(out, 0, (size_t)N * H * sizeof(float), stream);
        const long long sthreads = (long long)E * 32;
        scatter_kernel<<<(int)((sthreads + 255) / 256), 256, 0, stream>>>(
            x, ei, et, emb, out, E);
        gemm_ln_kernel<false><<<grid, 256, 0, stream>>>(
            x, nullptr, nullptr, Wself, bself, Wmsg, bmsg, gamma, beta, out, nTiles);
    }
}

// Round 4
// 335.761 us; speedup vs baseline: 3.6814x; 1.0115x over previous
//
#include <hip/hip_runtime.h>
#include <stdint.h>

#define H 128
#define TM 16
#define MAXDEG 24

typedef __attribute__((ext_vector_type(8))) short short8;
typedef __attribute__((ext_vector_type(4))) float f32x4;
typedef __attribute__((ext_vector_type(4))) int i32x4;

__device__ __forceinline__ unsigned short f2bf(float f) {
    union { float f; unsigned u; } v; v.f = f;
    unsigned u = v.u;
    u += 0x7fffu + ((u >> 16) & 1u);   // round-to-nearest-even
    return (unsigned short)(u >> 16);
}

__device__ __forceinline__ float bf2f(unsigned short u) {
    union { unsigned u; float f; } v; v.u = ((unsigned)u) << 16; return v.f;
}

__device__ __forceinline__ short8 cvt8(f32x4 a, f32x4 b) {
    short8 r;
    r[0] = (short)f2bf(a.x); r[1] = (short)f2bf(a.y);
    r[2] = (short)f2bf(a.z); r[3] = (short)f2bf(a.w);
    r[4] = (short)f2bf(b.x); r[5] = (short)f2bf(b.y);
    r[6] = (short)f2bf(b.z); r[7] = (short)f2bf(b.w);
    return r;
}

// ---------------------------------------------------------------------------
// prep = convert(x->bf16, emb->bf16)  UNION  CSR-lite build. One dispatch.
// Entry = src | (type << 18). Overflow nodes (cnt > MAXDEG) are handled by
// an in-kernel edge rescan in the consumer; no overflow list needed.
// ---------------------------------------------------------------------------
__global__ __launch_bounds__(256) void prep_kernel(
    const float* __restrict__ x, const float* __restrict__ emb,
    unsigned short* __restrict__ xb, unsigned short* __restrict__ embb,
    const int* __restrict__ ei, const int* __restrict__ et,
    int* __restrict__ cnt, int* __restrict__ bucket,
    int total8x, int total8e, int E)
{
    int i = blockIdx.x * 256 + threadIdx.x;
    if (i < total8x) {
        f32x4 a = ((const f32x4*)x)[2 * i];
        f32x4 b = ((const f32x4*)x)[2 * i + 1];
        ((short8*)xb)[i] = cvt8(a, b);
    } else if (i < total8x + total8e) {
        int j = i - total8x;
        f32x4 a = ((const f32x4*)emb)[2 * j];
        f32x4 b = ((const f32x4*)emb)[2 * j + 1];
        ((short8*)embb)[j] = cvt8(a, b);
    }
    if (i < E) {
        int src = ei[i];
        int dst = ei[E + i];
        int t   = et[i];
        int pos = atomicAdd(&cnt[dst], 1);
        if (pos < MAXDEG) bucket[(size_t)dst * MAXDEG + pos] = src | (t << 18);
    }
}

// ---------------------------------------------------------------------------
// Fused: per 16-node tile, gather+aggregate incoming edges (fp32 acc in
// registers, 16 lanes/node, 4-deep chunks) -> bf16 LDS A-tile alongside the
// staged x-half -> K=256 MFMA -> bias+relu -> LayerNorm -> NT store.
// ---------------------------------------------------------------------------
template<bool EMB_LDS>
__global__ __launch_bounds__(256) void fused_gemm_kernel(
    const unsigned short* __restrict__ xb, const unsigned short* __restrict__ embb,
    const int* __restrict__ cnt, const int* __restrict__ bucket,
    const int* __restrict__ ei, const int* __restrict__ et,
    const float* __restrict__ Wself, const float* __restrict__ bself,
    const float* __restrict__ Wmsg, const float* __restrict__ bmsg,
    const float* __restrict__ gamma, const float* __restrict__ beta,
    float* __restrict__ out, int nTiles, int E, int T)
{
    __shared__ __align__(16) short a_stage[TM * 264];  // 16 x (256+8 pad) bf16
    __shared__ __align__(16) float o_stage[TM * 132];  // 16 x (128+4 pad) f32
    __shared__ __align__(16) short emb_s[16 * 136];    // padded stride 136

    const int tid  = threadIdx.x;
    const int wave = tid >> 6;
    const int lane = tid & 63;
    const int col  = lane & 15;
    const int quad = lane >> 4;
    const int node = tid >> 4;   // 0..15
    const int l    = tid & 15;   // feature chunk: elements l*8 .. l*8+7

    if (EMB_LDS && tid < T * 16) {
        int t = tid >> 4;
        *(short8*)&emb_s[t * 136 + l * 8] = *(const short8*)(embb + t * H + l * 8);
    }

    // ---- B fragments (weights, bf16) into registers; once per block ----
    short8 bfrag[2][8];
    float bias[2];
#pragma unroll
    for (int s = 0; s < 2; ++s) {
        const int h = (wave * 2 + s) * 16 + col;
        bias[s] = bself[h] + bmsg[h];
#pragma unroll
        for (int kst = 0; kst < 8; ++kst) {
            const float* W = (kst < 4) ? Wself : Wmsg;
            const int k0 = (kst & 3) * 32 + quad * 8;
            const float* p = W + (size_t)h * H + k0;
            f32x4 w0 = *(const f32x4*)(p);
            f32x4 w1 = *(const f32x4*)(p + 4);
            bfrag[s][kst] = cvt8(w0, w1);
        }
    }

    const int f0 = l * 8;
    f32x4 g0  = *(const f32x4*)(gamma + f0);
    f32x4 g1  = *(const f32x4*)(gamma + f0 + 4);
    f32x4 be0 = *(const f32x4*)(beta + f0);
    f32x4 be1 = *(const f32x4*)(beta + f0 + 4);

    __syncthreads();   // emb_s visible

    for (int tile = blockIdx.x; tile < nTiles; tile += gridDim.x) {
        const size_t row = (size_t)tile * TM + node;

        // x-half stage load (independent of gather; issued early)
        short8 xv_st = *(const short8*)(xb + row * H + l * 8);

        // ---- gather + aggregate into fp32 registers ----
        int c = cnt[row];
        float acc[8] = {0.f, 0.f, 0.f, 0.f, 0.f, 0.f, 0.f, 0.f};
        if (c <= MAXDEG) {
            const int* b = bucket + row * MAXDEG;
            for (int i0 = 0; i0 < c; i0 += 4) {
                i32x4 p = *(const i32x4*)(b + i0);
                int rem = c - i0;
                bool h1 = rem > 1, h2 = rem > 2, h3 = rem > 3;
                short8 xv0, xv1, xv2, xv3, ev0, ev1, ev2, ev3;
                {
                    int s = p.x & 0x3FFFF, t = p.x >> 18;
                    xv0 = *(const short8*)(xb + (size_t)s * H + l * 8);
                    ev0 = EMB_LDS ? *(const short8*)&emb_s[t * 136 + l * 8]
                                  : *(const short8*)(embb + (size_t)t * H + l * 8);
                }
                if (h1) {
                    int s = p.y & 0x3FFFF, t = p.y >> 18;
                    xv1 = *(const short8*)(xb + (size_t)s * H + l * 8);
                    ev1 = EMB_LDS ? *(const short8*)&emb_s[t * 136 + l * 8]
                                  : *(const short8*)(embb + (size_t)t * H + l * 8);
                }
                if (h2) {
                    int s = p.z & 0x3FFFF, t = p.z >> 18;
                    xv2 = *(const short8*)(xb + (size_t)s * H + l * 8);
                    ev2 = EMB_LDS ? *(const short8*)&emb_s[t * 136 + l * 8]
                                  : *(const short8*)(embb + (size_t)t * H + l * 8);
                }
                if (h3) {
                    int s = p.w & 0x3FFFF, t = p.w >> 18;
                    xv3 = *(const short8*)(xb + (size_t)s * H + l * 8);
                    ev3 = EMB_LDS ? *(const short8*)&emb_s[t * 136 + l * 8]
                                  : *(const short8*)(embb + (size_t)t * H + l * 8);
                }
#pragma unroll
                for (int j = 0; j < 8; ++j) acc[j] += bf2f((unsigned short)xv0[j]) + bf2f((unsigned short)ev0[j]);
                if (h1) {
#pragma unroll
                    for (int j = 0; j < 8; ++j) acc[j] += bf2f((unsigned short)xv1[j]) + bf2f((unsigned short)ev1[j]);
                }
                if (h2) {
#pragma unroll
                    for (int j = 0; j < 8; ++j) acc[j] += bf2f((unsigned short)xv2[j]) + bf2f((unsigned short)ev2[j]);
                }
                if (h3) {
#pragma unroll
                    for (int j = 0; j < 8; ++j) acc[j] += bf2f((unsigned short)xv3[j]) + bf2f((unsigned short)ev3[j]);
                }
            }
        } else {
            // Overflow escape hatch (deg > MAXDEG): rescan full edge list.
            // Correct for any input; never triggered for Poisson(3) graphs.
            for (int e = 0; e < E; ++e) {
                if (ei[E + e] == (int)row) {
                    int s = ei[e], t = et[e];
                    short8 xv = *(const short8*)(xb + (size_t)s * H + l * 8);
                    short8 ev = EMB_LDS ? *(const short8*)&emb_s[t * 136 + l * 8]
                                        : *(const short8*)(embb + (size_t)t * H + l * 8);
#pragma unroll
                    for (int j = 0; j < 8; ++j) acc[j] += bf2f((unsigned short)xv[j]) + bf2f((unsigned short)ev[j]);
                }
            }
        }

        // ---- write both halves of the A-tile ----
        *(short8*)&a_stage[node * 264 + l * 8] = xv_st;
        short8 ar;
#pragma unroll
        for (int j = 0; j < 8; ++j) ar[j] = (short)f2bf(acc[j]);
        *(short8*)&a_stage[node * 264 + 128 + l * 8] = ar;
        __syncthreads();

        // ---- MFMA over K=256 ----
        short8 afr[8];
#pragma unroll
        for (int kst = 0; kst < 8; ++kst)
            afr[kst] = *(const short8*)(&a_stage[col * 264 + kst * 32 + quad * 8]);

        f32x4 acc0 = {0.f, 0.f, 0.f, 0.f};
        f32x4 acc1 = {0.f, 0.f, 0.f, 0.f};
#pragma unroll
        for (int kst = 0; kst < 8; ++kst) {
            acc0 = __builtin_amdgcn_mfma_f32_16x16x32_bf16(afr[kst], bfrag[0][kst], acc0, 0, 0, 0);
            acc1 = __builtin_amdgcn_mfma_f32_16x16x32_bf16(afr[kst], bfrag[1][kst], acc1, 0, 0, 0);
        }

        // ---- bias + relu -> o_stage ----
#pragma unroll
        for (int s = 0; s < 2; ++s) {
            const int h = (wave * 2 + s) * 16 + col;
            f32x4 a = s ? acc1 : acc0;
#pragma unroll
            for (int r = 0; r < 4; ++r) {
                const int m = quad * 4 + r;
                float v = a[r] + bias[s];
                o_stage[m * 132 + h] = v > 0.f ? v : 0.f;
            }
        }
        __syncthreads();

        // ---- LayerNorm per node (16 lanes/node, 8 feats/lane) ----
        float v[8];
        float s1 = 0.f, s2 = 0.f;
#pragma unroll
        for (int j = 0; j < 8; ++j) {
            v[j] = o_stage[node * 132 + f0 + j];
            s1 += v[j];
            s2 += v[j] * v[j];
        }
#pragma unroll
        for (int m = 1; m < 16; m <<= 1) {
            s1 += __shfl_xor(s1, m, 64);
            s2 += __shfl_xor(s2, m, 64);
        }
        const float mu = s1 * (1.f / 128.f);
        const float var = s2 * (1.f / 128.f) - mu * mu;
        const float rstd = rsqrtf(var + 1e-5f);

        f32x4 o0, o1;
        o0.x = (v[0] - mu) * rstd * g0.x + be0.x;
        o0.y = (v[1] - mu) * rstd * g0.y + be0.y;
        o0.z = (v[2] - mu) * rstd * g0.z + be0.z;
        o0.w = (v[3] - mu) * rstd * g0.w + be0.w;
        o1.x = (v[4] - mu) * rstd * g1.x + be1.x;
        o1.y = (v[5] - mu) * rstd * g1.y + be1.y;
        o1.z = (v[6] - mu) * rstd * g1.z + be1.z;
        o1.w = (v[7] - mu) * rstd * g1.w + be1.w;

        float* dst = out + row * H + f0;
        __builtin_nontemporal_store(o0, (f32x4*)dst);
        __builtin_nontemporal_store(o1, (f32x4*)(dst + 4));
    }
}

// ---------------------------------------------------------------------------
// Tier-C fallback: atomic scatter + fp32 gemm (agg staged in d_out).
// ---------------------------------------------------------------------------
__global__ __launch_bounds__(256) void scatter_kernel(
    const float* __restrict__ x, const int* __restrict__ ei,
    const int* __restrict__ et, const float* __restrict__ emb,
    float* __restrict__ agg, int E)
{
    int g = blockIdx.x * 256 + threadIdx.x;
    int e = g >> 5;
    int l = g & 31;
    if (e >= E) return;
    int src = ei[e];
    int dst = ei[E + e];
    int t   = et[e];
    f32x4 xv = *(const f32x4*)(x   + (size_t)src * H + l * 4);
    f32x4 ev = *(const f32x4*)(emb + (size_t)t   * H + l * 4);
    float* b = agg + (size_t)dst * H + l * 4;
    atomicAdd(b + 0, xv.x + ev.x);
    atomicAdd(b + 1, xv.y + ev.y);
    atomicAdd(b + 2, xv.z + ev.z);
    atomicAdd(b + 3, xv.w + ev.w);
}

__global__ __launch_bounds__(256) void gemm_ln_f32_kernel(
    const float* __restrict__ x,
    const float* __restrict__ Wself, const float* __restrict__ bself,
    const float* __restrict__ Wmsg, const float* __restrict__ bmsg,
    const float* __restrict__ gamma, const float* __restrict__ beta,
    float* __restrict__ out, int nTiles)
{
    __shared__ __align__(16) short a_stage[TM * 264];
    __shared__ __align__(16) float o_stage[TM * 132];

    const int tid  = threadIdx.x;
    const int wave = tid >> 6;
    const int lane = tid & 63;
    const int col  = lane & 15;
    const int quad = lane >> 4;

    short8 bfrag[2][8];
    float bias[2];
#pragma unroll
    for (int s = 0; s < 2; ++s) {
        const int h = (wave * 2 + s) * 16 + col;
        bias[s] = bself[h] + bmsg[h];
#pragma unroll
        for (int kst = 0; kst < 8; ++kst) {
            const float* W = (kst < 4) ? Wself : Wmsg;
            const int k0 = (kst & 3) * 32 + quad * 8;
            const float* p = W + (size_t)h * H + k0;
            f32x4 w0 = *(const f32x4*)(p);
            f32x4 w1 = *(const f32x4*)(p + 4);
            bfrag[s][kst] = cvt8(w0, w1);
        }
    }

    const int lnode = tid >> 4;
    const int f0 = (tid & 15) * 8;
    f32x4 g0  = *(const f32x4*)(gamma + f0);
    f32x4 g1  = *(const f32x4*)(gamma + f0 + 4);
    f32x4 be0 = *(const f32x4*)(beta + f0);
    f32x4 be1 = *(const f32x4*)(beta + f0 + 4);

    for (int tile = blockIdx.x; tile < nTiles; tile += gridDim.x) {
        const size_t rowBase = (size_t)tile * TM;
        {
            const int node = tid >> 4;
            const int seg  = tid & 15;
            const int k0   = seg * 16;
            const float* src = (seg < 8)
                ? (x   + (rowBase + node) * H + k0)
                : (out + (rowBase + node) * H + (k0 - 128));
            f32x4 v0 = ((const f32x4*)src)[0];
            f32x4 v1 = ((const f32x4*)src)[1];
            f32x4 v2 = ((const f32x4*)src)[2];
            f32x4 v3 = ((const f32x4*)src)[3];
            *(short8*)(&a_stage[node * 264 + k0])     = cvt8(v0, v1);
            *(short8*)(&a_stage[node * 264 + k0 + 8]) = cvt8(v2, v3);
        }
        __syncthreads();

        short8 afr[8];
#pragma unroll
        for (int kst = 0; kst < 8; ++kst)
            afr[kst] = *(const short8*)(&a_stage[col * 264 + kst * 32 + quad * 8]);

        f32x4 acc0 = {0.f, 0.f, 0.f, 0.f};
        f32x4 acc1 = {0.f, 0.f, 0.f, 0.f};
#pragma unroll
        for (int kst = 0; kst < 8; ++kst) {
            acc0 = __builtin_amdgcn_mfma_f32_16x16x32_bf16(afr[kst], bfrag[0][kst], acc0, 0, 0, 0);
            acc1 = __builtin_amdgcn_mfma_f32_16x16x32_bf16(afr[kst], bfrag[1][kst], acc1, 0, 0, 0);
        }

#pragma unroll
        for (int s = 0; s < 2; ++s) {
            const int h = (wave * 2 + s) * 16 + col;
            f32x4 a = s ? acc1 : acc0;
#pragma unroll
            for (int r = 0; r < 4; ++r) {
                const int m = quad * 4 + r;
                float v = a[r] + bias[s];
                o_stage[m * 132 + h] = v > 0.f ? v : 0.f;
            }
        }
        __syncthreads();

        float v[8];
        float s1 = 0.f, s2 = 0.f;
#pragma unroll
        for (int j = 0; j < 8; ++j) {
            v[j] = o_stage[lnode * 132 + f0 + j];
            s1 += v[j];
            s2 += v[j] * v[j];
        }
#pragma unroll
        for (int m = 1; m < 16; m <<= 1) {
            s1 += __shfl_xor(s1, m, 64);
            s2 += __shfl_xor(s2, m, 64);
        }
        const float mu = s1 * (1.f / 128.f);
        const float var = s2 * (1.f / 128.f) - mu * mu;
        const float rstd = rsqrtf(var + 1e-5f);

        f32x4 o0, o1;
        o0.x = (v[0] - mu) * rstd * g0.x + be0.x;
        o0.y = (v[1] - mu) * rstd * g0.y + be0.y;
        o0.z = (v[2] - mu) * rstd * g0.z + be0.z;
        o0.w = (v[3] - mu) * rstd * g0.w + be0.w;
        o1.x = (v[4] - mu) * rstd * g1.x + be1.x;
        o1.y = (v[5] - mu) * rstd * g1.y + be1.y;
        o1.z = (v[6] - mu) * rstd * g1.z + be1.z;
        o1.w = (v[7] - mu) * rstd * g1.w + be1.w;

        float* dst = out + (rowBase + lnode) * H + f0;
        *(f32x4*)(dst)     = o0;
        *(f32x4*)(dst + 4) = o1;
    }
}

extern "C" void kernel_launch(void* const* d_in, const int* in_sizes, int n_in,
                              void* d_out, int out_size, void* d_ws, size_t ws_size,
                              hipStream_t stream) {
    const float* x     = (const float*)d_in[0];
    const int*   ei    = (const int*)d_in[1];
    const int*   et    = (const int*)d_in[2];
    const float* emb   = (const float*)d_in[3];
    const float* Wself = (const float*)d_in[4];
    const float* bself = (const float*)d_in[5];
    const float* Wmsg  = (const float*)d_in[6];
    const float* bmsg  = (const float*)d_in[7];
    const float* gamma = (const float*)d_in[8];
    const float* beta  = (const float*)d_in[9];
    float* out = (float*)d_out;

    const int E = in_sizes[2];
    const int N = in_sizes[0] / H;
    const int T = in_sizes[3] / H;
    const int nTiles = N / TM;

    auto rnd = [](size_t b) { return (b + 255) & ~(size_t)255; };
    const size_t sz_xb   = rnd((size_t)N * H * 2);
    const size_t sz_embb = rnd((size_t)T * H * 2);
    const size_t sz_cnt  = rnd((size_t)N * 4);
    const size_t sz_bkt  = rnd((size_t)N * MAXDEG * 4);
    const size_t needA = sz_xb + sz_embb + sz_cnt + sz_bkt;

    const bool tierA = (ws_size >= needA) && (N <= (1 << 18)) && (T <= 4096)
                       && (N % TM == 0);

    if (tierA) {
        uint8_t* p = (uint8_t*)d_ws;
        unsigned short* xb   = (unsigned short*)p;  p += sz_xb;
        unsigned short* embb = (unsigned short*)p;  p += sz_embb;
        int* cnt    = (int*)p;                      p += sz_cnt;
        int* bucket = (int*)p;

        hipMemsetAsync(cnt, 0, (size_t)N * sizeof(int), stream);

        const int t8x = N * H / 8, t8e = T * H / 8;
        int prepWork = (t8x + t8e) > E ? (t8x + t8e) : E;
        prep_kernel<<<(prepWork + 255) / 256, 256, 0, stream>>>(
            x, emb, xb, embb, ei, et, cnt, bucket, t8x, t8e, E);

        int grid = 3125;
        if (grid > nTiles) grid = nTiles;
        if (T <= 16) {
            fused_gemm_kernel<true><<<grid, 256, 0, stream>>>(
                xb, embb, cnt, bucket, ei, et,
                Wself, bself, Wmsg, bmsg, gamma, beta, out, nTiles, E, T);
        } else {
            fused_gemm_kernel<false><<<grid, 256, 0, stream>>>(
                xb, embb, cnt, bucket, ei, et,
                Wself, bself, Wmsg, bmsg, gamma, beta, out, nTiles, E, T);
        }
    } else {
        // Tier C: atomic scatter into d_out, then fp32 gemm reading agg from d_out.
        hipMemsetAsync(out, 0, (size_t)N * H * sizeof(float), stream);
        const long long sthreads = (long long)E * 32;
        scatter_kernel<<<(int)((sthreads + 255) / 256), 256, 0, stream>>>(
            x, ei, et, emb, out, E);
        int grid = 2500;
        if (grid > nTiles) grid = nTiles;
        gemm_ln_f32_kernel<<<grid, 256, 0, stream>>>(
            x, Wself, bself, Wmsg, bmsg, gamma, beta, out, nTiles);
    }
}